// Round 3
// baseline (288.874 us; speedup 1.0000x reference)
//
#include <hip/hip_runtime.h>

#define LOG2E 1.4426950408889634f

typedef unsigned long long u64;
typedef unsigned int uint;
typedef unsigned short ushort_t;
typedef __attribute__((ext_vector_type(8))) short short8;
typedef __attribute__((ext_vector_type(4))) float floatx4;
typedef __attribute__((ext_vector_type(4))) unsigned short ushort4v;

#define GN 4096
#define GH 256

__device__ __forceinline__ ushort_t f2bf(float f){
  uint u = __float_as_uint(f);
  u += 0x7FFFu + ((u >> 16) & 1u);
  return (ushort_t)(u >> 16);
}
__device__ __forceinline__ float bf2f(ushort_t h){
  return __uint_as_float(((uint)h) << 16);
}
__device__ __forceinline__ float exp2_(float x){
#if __has_builtin(__builtin_amdgcn_exp2f)
  return __builtin_amdgcn_exp2f(x);
#else
  return exp2f(x);
#endif
}

// ---------------- adj (int32 0/1) -> bitmask u64[4096][64] ----------------
__global__ __launch_bounds__(256) void pack_mask(const int* __restrict__ adj,
                                                 u64* __restrict__ mask){
  const int lane = threadIdx.x & 63;
  const int i = blockIdx.x * 4 + (threadIdx.x >> 6);
  const int* row = adj + (size_t)i * GN;
  for (int w = 0; w < 64; ++w){
    int v = row[w * 64 + lane];
    u64 b = __ballot(v > 0);
    if (lane == 0) mask[(size_t)i * 64 + w] = b;
  }
}

// ---- transpose f32 [R][C] -> split bf16 hi/lo planes [C][R] --------------
__global__ __launch_bounds__(256) void transpose_split(const float* __restrict__ in,
                                                       ushort_t* __restrict__ hi,
                                                       ushort_t* __restrict__ lo,
                                                       int R, int C){
  __shared__ ushort_t th[32][33];
  __shared__ ushort_t tl[32][33];
  const int ctiles = C >> 5;
  const int bx = blockIdx.x % ctiles;
  const int by = blockIdx.x / ctiles;
  const int i0 = by * 32, j0 = bx * 32;
  const int r = threadIdx.x >> 3, c4 = (threadIdx.x & 7) * 4;
  floatx4 v = *(const floatx4*)(in + (size_t)(i0 + r) * C + j0 + c4);
  #pragma unroll
  for (int e = 0; e < 4; ++e){
    ushort_t h = f2bf(v[e]);
    th[r][c4 + e] = h;
    tl[r][c4 + e] = f2bf(v[e] - bf2f(h));
  }
  __syncthreads();
  ushort4v oh, ol;
  #pragma unroll
  for (int e = 0; e < 4; ++e){ oh[e] = th[c4 + e][r]; ol[e] = tl[c4 + e][r]; }
  *(ushort4v*)(hi + (size_t)(j0 + r) * R + i0 + c4) = oh;
  *(ushort4v*)(lo + (size_t)(j0 + r) * R + i0 + c4) = ol;
}

// --- split-bf16 GEMM (~f32 quality): Cf[M][256] = A_f32[M][K] @ BT^T ------
// B pre-split planes BThi/BTlo [256][K]; A split on the fly during staging.
__global__ __launch_bounds__(256) void gemm_split(const float* __restrict__ A,
                                                  const ushort_t* __restrict__ BThi,
                                                  const ushort_t* __restrict__ BTlo,
                                                  float* __restrict__ Cf, int K){
  __shared__ short8 AhiV[64 * 8];
  __shared__ short8 AloV[64 * 8];
  __shared__ short8 BhiV[64 * 8];
  __shared__ short8 BloV[64 * 8];
  char* Ahi = (char*)AhiV; char* Alo = (char*)AloV;
  char* Bhi = (char*)BhiV; char* Blo = (char*)BloV;
  const int tid = threadIdx.x;
  const int i0 = blockIdx.y * 64, n0 = blockIdx.x * 64;
  const int lane = tid & 63, wave = tid >> 6;
  const int wr = wave & 1, wc = wave >> 1;
  const int l15 = lane & 15, lhi = lane >> 4;
  const int rs = tid >> 3, ch = tid & 7;
  floatx4 acc[2][2] = {};
  for (int kb = 0; kb < K; kb += 64){
    #pragma unroll
    for (int q = 0; q < 2; ++q){
      int r = rs + q * 32;
      floatx4 f0 = *(const floatx4*)(A + (size_t)(i0 + r) * K + kb + ch * 8);
      floatx4 f1 = *(const floatx4*)(A + (size_t)(i0 + r) * K + kb + ch * 8 + 4);
      short8 ah, al;
      #pragma unroll
      for (int e = 0; e < 4; ++e){
        ushort_t h0 = f2bf(f0[e]); ah[e] = (short)h0; al[e] = (short)f2bf(f0[e] - bf2f(h0));
        ushort_t h1 = f2bf(f1[e]); ah[e+4] = (short)h1; al[e+4] = (short)f2bf(f1[e] - bf2f(h1));
      }
      const int sw = (ch * 16) ^ ((r & 7) << 4);
      *(short8*)(Ahi + r * 128 + sw) = ah;
      *(short8*)(Alo + r * 128 + sw) = al;
      short8 bh = *(const short8*)(BThi + (size_t)(n0 + r) * K + kb + ch * 8);
      short8 bl = *(const short8*)(BTlo + (size_t)(n0 + r) * K + kb + ch * 8);
      *(short8*)(Bhi + r * 128 + sw) = bh;
      *(short8*)(Blo + r * 128 + sw) = bl;
    }
    __syncthreads();
    #pragma unroll
    for (int kt = 0; kt < 2; ++kt){
      int klb = (kt * 32 + lhi * 8) * 2;
      short8 ah[2], al[2], bh[2], bl[2];
      #pragma unroll
      for (int m = 0; m < 2; ++m){
        int rowA = wr * 32 + m * 16 + l15;
        int swA = klb ^ ((rowA & 7) << 4);
        ah[m] = *(const short8*)(Ahi + rowA * 128 + swA);
        al[m] = *(const short8*)(Alo + rowA * 128 + swA);
        int rowB = wc * 32 + m * 16 + l15;
        int swB = klb ^ ((rowB & 7) << 4);
        bh[m] = *(const short8*)(Bhi + rowB * 128 + swB);
        bl[m] = *(const short8*)(Blo + rowB * 128 + swB);
      }
      #pragma unroll
      for (int m = 0; m < 2; ++m)
        #pragma unroll
        for (int n = 0; n < 2; ++n){
          acc[m][n] = __builtin_amdgcn_mfma_f32_16x16x32_bf16(ah[m], bh[n], acc[m][n], 0, 0, 0);
          acc[m][n] = __builtin_amdgcn_mfma_f32_16x16x32_bf16(ah[m], bl[n], acc[m][n], 0, 0, 0);
          acc[m][n] = __builtin_amdgcn_mfma_f32_16x16x32_bf16(al[m], bh[n], acc[m][n], 0, 0, 0);
        }
    }
    __syncthreads();
  }
  #pragma unroll
  for (int m = 0; m < 2; ++m)
    #pragma unroll
    for (int rr = 0; rr < 4; ++rr){
      int row = i0 + wr * 32 + m * 16 + lhi * 4 + rr;
      #pragma unroll
      for (int n = 0; n < 2; ++n){
        int col = n0 + wc * 32 + n * 16 + l15;
        Cf[(size_t)row * GH + col] = acc[m][n][rr];
      }
    }
}

// ---------- per-row s_src, s_dst (pre-scaled by log2e) from f32 Wh --------
__global__ __launch_bounds__(256) void skernel(const float* __restrict__ Whf,
                                               const float* __restrict__ asrc,
                                               const float* __restrict__ adst,
                                               float* __restrict__ ss,
                                               float* __restrict__ sd){
  const int lane = threadIdx.x & 63;
  const int i = blockIdx.x * 4 + (threadIdx.x >> 6);
  floatx4 w = *(const floatx4*)(Whf + (size_t)i * GH + lane * 4);
  floatx4 s4 = *(const floatx4*)(asrc + lane * 4);
  floatx4 d4 = *(const floatx4*)(adst + lane * 4);
  float s = 0.f, d = 0.f;
  #pragma unroll
  for (int e = 0; e < 4; ++e){
    s += w[e] * s4[e]; d += w[e] * d4[e];
  }
  #pragma unroll
  for (int off = 32; off; off >>= 1){
    s += __shfl_xor(s, off);
    d += __shfl_xor(d, off);
  }
  if (lane == 0){ ss[i] = s * LOG2E; sd[i] = d * LOG2E; }
}

// --------- per-row masked max (m) and inv exp-sum (1/l), scaled domain ----
__global__ __launch_bounds__(256) void rowstats(const u64* __restrict__ mask,
                                                const float* __restrict__ ss,
                                                const float* __restrict__ sd,
                                                float* __restrict__ mm,
                                                float* __restrict__ linv){
  const int lane = threadIdx.x & 63;
  const int i = blockIdx.x * 4 + (threadIdx.x >> 6);
  const u64* mrow = mask + (size_t)i * 64;
  float mx = -3.0e38f;
  for (int it = 0; it < 64; ++it){
    u64 word = mrow[it];
    float v = sd[it * 64 + lane];
    uint bit = (uint)(word >> lane) & 1u;
    mx = fmaxf(mx, bit ? v : -3.0e38f);
  }
  #pragma unroll
  for (int off = 32; off; off >>= 1) mx = fmaxf(mx, __shfl_xor(mx, off));
  const float ssi = ss[i];
  float targ = ssi + mx;
  float mmv = fmaxf(targ, 0.2f * targ);
  float sum = 0.f;
  for (int it = 0; it < 64; ++it){
    u64 word = mrow[it];
    float v = sd[it * 64 + lane];
    uint bit = (uint)(word >> lane) & 1u;
    float a = ssi + v;
    float lr = fmaxf(a, 0.2f * a);
    float p = exp2_(lr - mmv);
    sum += bit ? p : 0.f;
  }
  #pragma unroll
  for (int off = 32; off; off >>= 1) sum += __shfl_xor(sum, off);
  if (lane == 0){ mm[i] = mmv; linv[i] = sum > 0.f ? 1.0f / sum : 0.f; }
}

// ----- fused PV (split-bf16, ~f32): out = softmax-P @ Wh, +ReLU -----------
__global__ __launch_bounds__(256) void gat_pv(const u64* __restrict__ mask,
                                              const float* __restrict__ ss,
                                              const float* __restrict__ sd,
                                              const float* __restrict__ mm,
                                              const float* __restrict__ linv,
                                              const ushort_t* __restrict__ VThi,
                                              const ushort_t* __restrict__ VTlo,
                                              float* __restrict__ outb){
  __shared__ short8 BhiV[128 * 8];
  __shared__ short8 BloV[128 * 8];
  __shared__ short8 PhiV[32 * 8];
  __shared__ short8 PloV[32 * 8];
  char* Bhi = (char*)BhiV; char* Blo = (char*)BloV;
  char* Phi = (char*)PhiV; char* Plo = (char*)PloV;
  const int tid = threadIdx.x;
  const int i0 = blockIdx.y * 32;
  const int n0 = blockIdx.x * 128;
  const int lane = tid & 63, wave = tid >> 6;
  const int wr = wave & 1, wc = wave >> 1;
  const int l15 = lane & 15, lhi = lane >> 4;
  const int pr = tid >> 3, pj8 = tid & 7;
  const int prow = i0 + pr;
  const float ssi = ss[prow];
  const float mmi = mm[prow];
  const u64* mrow = mask + (size_t)prow * 64;
  floatx4 acc[4] = {};
  for (int kb = 0; kb < 64; ++kb){
    // B tile loads (registers; VMEM overlaps P-build VALU)
    short8 bregh[4], bregl[4];
    #pragma unroll
    for (int q = 0; q < 4; ++q){
      int c = pr + q * 32;
      bregh[q] = *(const short8*)(VThi + (size_t)(n0 + c) * GN + kb * 64 + pj8 * 8);
      bregl[q] = *(const short8*)(VTlo + (size_t)(n0 + c) * GN + kb * 64 + pj8 * 8);
    }
    // P build: p = adj ? exp2(lrelu(ss+sd) - m) : 0 ; split hi/lo
    u64 word = mrow[kb];
    floatx4 s0 = *(const floatx4*)(sd + kb * 64 + pj8 * 8);
    floatx4 s1 = *(const floatx4*)(sd + kb * 64 + pj8 * 8 + 4);
    short8 pvh, pvl;
    const int shbase = pj8 * 8;
    #pragma unroll
    for (int e = 0; e < 8; ++e){
      float sv = (e < 4) ? s0[e] : s1[e - 4];
      float targ = ssi + sv;
      float lr = fmaxf(targ, 0.2f * targ);
      float p = exp2_(lr - mmi);
      uint bit = (uint)(word >> (shbase + e)) & 1u;
      p = bit ? p : 0.0f;
      ushort_t h = f2bf(p);
      pvh[e] = (short)h;
      pvl[e] = (short)f2bf(p - bf2f(h));
    }
    const int swP = (pj8 * 16) ^ ((pr & 7) << 4);
    *(short8*)(Phi + pr * 128 + swP) = pvh;
    *(short8*)(Plo + pr * 128 + swP) = pvl;
    #pragma unroll
    for (int q = 0; q < 4; ++q){
      int c = pr + q * 32;
      const int swB = (pj8 * 16) ^ ((c & 7) << 4);
      *(short8*)(Bhi + c * 128 + swB) = bregh[q];
      *(short8*)(Blo + c * 128 + swB) = bregl[q];
    }
    __syncthreads();
    #pragma unroll
    for (int kt = 0; kt < 2; ++kt){
      int klb = (kt * 32 + lhi * 8) * 2;
      int rowA = wr * 16 + l15;
      int swA = klb ^ ((rowA & 7) << 4);
      short8 ah = *(const short8*)(Phi + rowA * 128 + swA);
      short8 al = *(const short8*)(Plo + rowA * 128 + swA);
      #pragma unroll
      for (int n = 0; n < 4; ++n){
        int rowB = wc * 64 + n * 16 + l15;
        int swB = klb ^ ((rowB & 7) << 4);
        short8 bh = *(const short8*)(Bhi + rowB * 128 + swB);
        short8 bl = *(const short8*)(Blo + rowB * 128 + swB);
        acc[n] = __builtin_amdgcn_mfma_f32_16x16x32_bf16(ah, bh, acc[n], 0, 0, 0);
        acc[n] = __builtin_amdgcn_mfma_f32_16x16x32_bf16(ah, bl, acc[n], 0, 0, 0);
        acc[n] = __builtin_amdgcn_mfma_f32_16x16x32_bf16(al, bh, acc[n], 0, 0, 0);
      }
    }
    __syncthreads();
  }
  float li[4];
  #pragma unroll
  for (int rr = 0; rr < 4; ++rr) li[rr] = linv[i0 + wr * 16 + lhi * 4 + rr];
  #pragma unroll
  for (int n = 0; n < 4; ++n){
    int col = n0 + wc * 64 + n * 16 + l15;
    #pragma unroll
    for (int rr = 0; rr < 4; ++rr){
      float v = fmaxf(acc[n][rr] * li[rr], 0.0f);
      outb[(size_t)(i0 + wr * 16 + lhi * 4 + rr) * GH + col] = v;
    }
  }
}

// ---- BN stats: per-32-row-block sum + M2 (shifted, stable) per column ----
__global__ __launch_bounds__(256) void colpart(const float* __restrict__ outb,
                                               float* __restrict__ part,
                                               float* __restrict__ partm2){
  const int c = threadIdx.x;
  const int b = blockIdx.x;
  float v[32];
  #pragma unroll
  for (int r = 0; r < 32; ++r) v[r] = outb[(size_t)(b * 32 + r) * GH + c];
  float s = 0.f;
  #pragma unroll
  for (int r = 0; r < 32; ++r) s += v[r];
  const float mu = s * (1.0f / 32.0f);
  float m2 = 0.f;
  #pragma unroll
  for (int r = 0; r < 32; ++r){ float d = v[r] - mu; m2 += d * d; }
  part[b * GH + c] = s;
  partm2[b * GH + c] = m2;
}

// ---- combine block stats (Chan) in f64 -> per-column scale/bias ----------
__global__ __launch_bounds__(256) void colfin(const float* __restrict__ part,
                                              const float* __restrict__ partm2,
                                              const float* __restrict__ gamma,
                                              const float* __restrict__ beta,
                                              float* __restrict__ scale,
                                              float* __restrict__ bias){
  const int c = threadIdx.x;
  double S = 0.0;
  for (int b = 0; b < 128; ++b) S += (double)part[b * GH + c];
  const double mean = S * (1.0 / 4096.0);
  double M2 = 0.0;
  for (int b = 0; b < 128; ++b){
    double mb = (double)part[b * GH + c] * (1.0 / 32.0);
    double d = mb - mean;
    M2 += (double)partm2[b * GH + c] + 32.0 * d * d;
  }
  const double var = M2 * (1.0 / 4096.0);
  float sc = gamma[c] * (float)(1.0 / sqrt(var + 1e-5));
  scale[c] = sc;
  bias[c] = beta[c] - (float)mean * sc;
}

// ------------------- apply BN: h*scale + bias -> f32 ----------------------
__global__ __launch_bounds__(256) void bnapply(const float* __restrict__ outb,
                                               const float* __restrict__ scale,
                                               const float* __restrict__ bias,
                                               float* __restrict__ dst){
  const int base = (blockIdx.x * 256 + threadIdx.x) * 4;
  const int c = base & (GH - 1);
  floatx4 v = *(const floatx4*)(outb + base);
  floatx4 s = *(const floatx4*)(scale + c);
  floatx4 b = *(const floatx4*)(bias + c);
  #pragma unroll
  for (int e = 0; e < 4; ++e) v[e] = v[e] * s[e] + b[e];
  *(floatx4*)(dst + base) = v;
}

extern "C" void kernel_launch(void* const* d_in, const int* in_sizes, int n_in,
                              void* d_out, int out_size, void* d_ws, size_t ws_size,
                              hipStream_t stream) {
  const float* x      = (const float*)d_in[0];
  const int*   adj    = (const int*)d_in[1];
  const float* W1     = (const float*)d_in[2];
  const float* a1s    = (const float*)d_in[3];
  const float* a1d    = (const float*)d_in[4];
  const float* g1     = (const float*)d_in[5];
  const float* b1     = (const float*)d_in[6];
  const float* W2     = (const float*)d_in[7];
  const float* a2s    = (const float*)d_in[8];
  const float* a2d    = (const float*)d_in[9];
  const float* g2     = (const float*)d_in[10];
  const float* b2     = (const float*)d_in[11];

  char* w = (char*)d_ws;
  auto alloc = [&](size_t bytes){ void* p = (void*)w; w += (bytes + 255) & ~(size_t)255; return p; };
  u64*      mask   = (u64*)alloc((size_t)GN * 64 * 8);         // 2 MB
  ushort_t* W1Th   = (ushort_t*)alloc((size_t)GH * 512 * 2);   // 256 KB
  ushort_t* W1Tl   = (ushort_t*)alloc((size_t)GH * 512 * 2);   // 256 KB
  ushort_t* W2Th   = (ushort_t*)alloc((size_t)GH * GH * 2);    // 128 KB
  ushort_t* W2Tl   = (ushort_t*)alloc((size_t)GH * GH * 2);    // 128 KB
  float*    Whf    = (float*)alloc((size_t)GN * GH * 4);       // 4 MB
  ushort_t* WTh    = (ushort_t*)alloc((size_t)GH * GN * 2);    // 2 MB
  ushort_t* WTl    = (ushort_t*)alloc((size_t)GH * GN * 2);    // 2 MB
  float*    hf     = (float*)alloc((size_t)GN * GH * 4);       // 4 MB
  float*    outb   = (float*)alloc((size_t)GN * GH * 4);       // 4 MB
  float*    ssb    = (float*)alloc(GN * 4);
  float*    sdb    = (float*)alloc(GN * 4);
  float*    mmb    = (float*)alloc(GN * 4);
  float*    linvb  = (float*)alloc(GN * 4);
  float*    part   = (float*)alloc(128 * GH * 4);
  float*    partm2 = (float*)alloc(128 * GH * 4);
  float*    scale  = (float*)alloc(GH * 4);
  float*    bias   = (float*)alloc(GH * 4);

  pack_mask<<<1024, 256, 0, stream>>>(adj, mask);
  transpose_split<<<(512/32)*(GH/32), 256, 0, stream>>>(W1, W1Th, W1Tl, 512, GH);
  transpose_split<<<(GH/32)*(GH/32), 256, 0, stream>>>(W2, W2Th, W2Tl, GH, GH);

  // ---- layer 1 ----
  gemm_split<<<dim3(4, 64), 256, 0, stream>>>(x, W1Th, W1Tl, Whf, 512);
  skernel<<<1024, 256, 0, stream>>>(Whf, a1s, a1d, ssb, sdb);
  transpose_split<<<(GN/32)*(GH/32), 256, 0, stream>>>(Whf, WTh, WTl, GN, GH);
  rowstats<<<1024, 256, 0, stream>>>(mask, ssb, sdb, mmb, linvb);
  gat_pv<<<dim3(2, 128), 256, 0, stream>>>(mask, ssb, sdb, mmb, linvb, WTh, WTl, outb);
  colpart<<<128, 256, 0, stream>>>(outb, part, partm2);
  colfin<<<1, 256, 0, stream>>>(part, partm2, g1, b1, scale, bias);
  bnapply<<<1024, 256, 0, stream>>>(outb, scale, bias, hf);

  // ---- layer 2 ----
  gemm_split<<<dim3(4, 64), 256, 0, stream>>>(hf, W2Th, W2Tl, Whf, 256);
  skernel<<<1024, 256, 0, stream>>>(Whf, a2s, a2d, ssb, sdb);
  transpose_split<<<(GN/32)*(GH/32), 256, 0, stream>>>(Whf, WTh, WTl, GN, GH);
  rowstats<<<1024, 256, 0, stream>>>(mask, ssb, sdb, mmb, linvb);
  gat_pv<<<dim3(2, 128), 256, 0, stream>>>(mask, ssb, sdb, mmb, linvb, WTh, WTl, outb);
  colpart<<<128, 256, 0, stream>>>(outb, part, partm2);
  colfin<<<1, 256, 0, stream>>>(part, partm2, g2, b2, scale, bias);
  bnapply<<<1024, 256, 0, stream>>>(outb, scale, bias, (float*)d_out);
}

// Round 4
// 220.988 us; speedup vs baseline: 1.3072x; 1.3072x over previous
//
#include <hip/hip_runtime.h>

#define LOG2E 1.4426950408889634f

typedef unsigned long long u64;
typedef unsigned int uint;
typedef unsigned short ushort_t;
typedef __attribute__((ext_vector_type(8))) short short8;
typedef __attribute__((ext_vector_type(4))) float floatx4;
typedef __attribute__((ext_vector_type(4))) unsigned short ushort4v;

#define GN 4096
#define GH 256
#define PV_SPLIT 4
#define PV_KB (64 / PV_SPLIT)

__device__ __forceinline__ ushort_t f2bf(float f){
  uint u = __float_as_uint(f);
  u += 0x7FFFu + ((u >> 16) & 1u);
  return (ushort_t)(u >> 16);
}
__device__ __forceinline__ float bf2f(ushort_t h){
  return __uint_as_float(((uint)h) << 16);
}
__device__ __forceinline__ float exp2_(float x){
#if __has_builtin(__builtin_amdgcn_exp2f)
  return __builtin_amdgcn_exp2f(x);
#else
  return exp2f(x);
#endif
}

// ---------------- adj (int32 0/1) -> bitmask u64[4096][64] ----------------
__global__ __launch_bounds__(256) void pack_mask(const int* __restrict__ adj,
                                                 u64* __restrict__ mask){
  const int lane = threadIdx.x & 63;
  const int i = blockIdx.x * 4 + (threadIdx.x >> 6);
  const int* row = adj + (size_t)i * GN;
  for (int w = 0; w < 64; ++w){
    int v = row[w * 64 + lane];
    u64 b = __ballot(v > 0);
    if (lane == 0) mask[(size_t)i * 64 + w] = b;
  }
}

// ---- transpose f32 [R][C] -> split bf16 hi/lo planes [C][R] --------------
__global__ __launch_bounds__(256) void transpose_split(const float* __restrict__ in,
                                                       ushort_t* __restrict__ hi,
                                                       ushort_t* __restrict__ lo,
                                                       int R, int C){
  __shared__ ushort_t th[32][33];
  __shared__ ushort_t tl[32][33];
  const int ctiles = C >> 5;
  const int bx = blockIdx.x % ctiles;
  const int by = blockIdx.x / ctiles;
  const int i0 = by * 32, j0 = bx * 32;
  const int r = threadIdx.x >> 3, c4 = (threadIdx.x & 7) * 4;
  floatx4 v = *(const floatx4*)(in + (size_t)(i0 + r) * C + j0 + c4);
  #pragma unroll
  for (int e = 0; e < 4; ++e){
    ushort_t h = f2bf(v[e]);
    th[r][c4 + e] = h;
    tl[r][c4 + e] = f2bf(v[e] - bf2f(h));
  }
  __syncthreads();
  ushort4v oh, ol;
  #pragma unroll
  for (int e = 0; e < 4; ++e){ oh[e] = th[c4 + e][r]; ol[e] = tl[c4 + e][r]; }
  *(ushort4v*)(hi + (size_t)(j0 + r) * R + i0 + c4) = oh;
  *(ushort4v*)(lo + (size_t)(j0 + r) * R + i0 + c4) = ol;
}

// --- split-bf16 GEMM (~f32): Cf[M][256] = A_f32[M][K] @ BT^T --------------
// 32x64 tile, 512 blocks (2/CU). B pre-split planes; A split on the fly.
__global__ __launch_bounds__(256) void gemm_split(const float* __restrict__ A,
                                                  const ushort_t* __restrict__ BThi,
                                                  const ushort_t* __restrict__ BTlo,
                                                  float* __restrict__ Cf, int K){
  __shared__ short8 AhiV[32 * 8];
  __shared__ short8 AloV[32 * 8];
  __shared__ short8 BhiV[64 * 8];
  __shared__ short8 BloV[64 * 8];
  char* Ahi = (char*)AhiV; char* Alo = (char*)AloV;
  char* Bhi = (char*)BhiV; char* Blo = (char*)BloV;
  const int tid = threadIdx.x;
  const int i0 = blockIdx.y * 32, n0 = blockIdx.x * 64;
  const int lane = tid & 63, wave = tid >> 6;
  const int wr = wave & 1, wc = wave >> 1;
  const int l15 = lane & 15, lhi = lane >> 4;
  const int rs = tid >> 3, ch = tid & 7;
  floatx4 acc[2] = {};
  for (int kb = 0; kb < K; kb += 64){
    {
      int r = rs;
      floatx4 f0 = *(const floatx4*)(A + (size_t)(i0 + r) * K + kb + ch * 8);
      floatx4 f1 = *(const floatx4*)(A + (size_t)(i0 + r) * K + kb + ch * 8 + 4);
      short8 ah, al;
      #pragma unroll
      for (int e = 0; e < 4; ++e){
        ushort_t h0 = f2bf(f0[e]); ah[e] = (short)h0; al[e] = (short)f2bf(f0[e] - bf2f(h0));
        ushort_t h1 = f2bf(f1[e]); ah[e+4] = (short)h1; al[e+4] = (short)f2bf(f1[e] - bf2f(h1));
      }
      const int sw = (ch * 16) ^ ((r & 7) << 4);
      *(short8*)(Ahi + r * 128 + sw) = ah;
      *(short8*)(Alo + r * 128 + sw) = al;
      #pragma unroll
      for (int q = 0; q < 2; ++q){
        int rb = rs + q * 32;
        const int swb = (ch * 16) ^ ((rb & 7) << 4);
        short8 bh = *(const short8*)(BThi + (size_t)(n0 + rb) * K + kb + ch * 8);
        short8 bl = *(const short8*)(BTlo + (size_t)(n0 + rb) * K + kb + ch * 8);
        *(short8*)(Bhi + rb * 128 + swb) = bh;
        *(short8*)(Blo + rb * 128 + swb) = bl;
      }
    }
    __syncthreads();
    #pragma unroll
    for (int kt = 0; kt < 2; ++kt){
      int klb = (kt * 32 + lhi * 8) * 2;
      int rowA = wr * 16 + l15;
      int swA = klb ^ ((rowA & 7) << 4);
      short8 ah = *(const short8*)(Ahi + rowA * 128 + swA);
      short8 al = *(const short8*)(Alo + rowA * 128 + swA);
      #pragma unroll
      for (int n = 0; n < 2; ++n){
        int rowB = wc * 32 + n * 16 + l15;
        int swB = klb ^ ((rowB & 7) << 4);
        short8 bh = *(const short8*)(Bhi + rowB * 128 + swB);
        short8 bl = *(const short8*)(Blo + rowB * 128 + swB);
        acc[n] = __builtin_amdgcn_mfma_f32_16x16x32_bf16(ah, bh, acc[n], 0, 0, 0);
        acc[n] = __builtin_amdgcn_mfma_f32_16x16x32_bf16(ah, bl, acc[n], 0, 0, 0);
        acc[n] = __builtin_amdgcn_mfma_f32_16x16x32_bf16(al, bh, acc[n], 0, 0, 0);
      }
    }
    __syncthreads();
  }
  #pragma unroll
  for (int rr = 0; rr < 4; ++rr){
    int row = i0 + wr * 16 + lhi * 4 + rr;
    #pragma unroll
    for (int n = 0; n < 2; ++n){
      int col = n0 + wc * 32 + n * 16 + l15;
      Cf[(size_t)row * GH + col] = acc[n][rr];
    }
  }
}

// ---------- per-row s_src, s_dst (pre-scaled by log2e) from f32 Wh --------
__global__ __launch_bounds__(256) void skernel(const float* __restrict__ Whf,
                                               const float* __restrict__ asrc,
                                               const float* __restrict__ adst,
                                               float* __restrict__ ss,
                                               float* __restrict__ sd){
  const int lane = threadIdx.x & 63;
  const int i = blockIdx.x * 4 + (threadIdx.x >> 6);
  floatx4 w = *(const floatx4*)(Whf + (size_t)i * GH + lane * 4);
  floatx4 s4 = *(const floatx4*)(asrc + lane * 4);
  floatx4 d4 = *(const floatx4*)(adst + lane * 4);
  float s = 0.f, d = 0.f;
  #pragma unroll
  for (int e = 0; e < 4; ++e){
    s += w[e] * s4[e]; d += w[e] * d4[e];
  }
  #pragma unroll
  for (int off = 32; off; off >>= 1){
    s += __shfl_xor(s, off);
    d += __shfl_xor(d, off);
  }
  if (lane == 0){ ss[i] = s * LOG2E; sd[i] = d * LOG2E; }
}

// --------- per-row masked max (m) and inv exp-sum (1/l), scaled domain ----
__global__ __launch_bounds__(256) void rowstats(const u64* __restrict__ mask,
                                                const float* __restrict__ ss,
                                                const float* __restrict__ sd,
                                                float* __restrict__ mm,
                                                float* __restrict__ linv){
  const int lane = threadIdx.x & 63;
  const int i = blockIdx.x * 4 + (threadIdx.x >> 6);
  const u64* mrow = mask + (size_t)i * 64;
  float mx = -3.0e38f;
  for (int it = 0; it < 64; ++it){
    u64 word = mrow[it];
    float v = sd[it * 64 + lane];
    uint bit = (uint)(word >> lane) & 1u;
    mx = fmaxf(mx, bit ? v : -3.0e38f);
  }
  #pragma unroll
  for (int off = 32; off; off >>= 1) mx = fmaxf(mx, __shfl_xor(mx, off));
  const float ssi = ss[i];
  float targ = ssi + mx;
  float mmv = fmaxf(targ, 0.2f * targ);
  float sum = 0.f;
  for (int it = 0; it < 64; ++it){
    u64 word = mrow[it];
    float v = sd[it * 64 + lane];
    uint bit = (uint)(word >> lane) & 1u;
    float a = ssi + v;
    float lr = fmaxf(a, 0.2f * a);
    float p = exp2_(lr - mmv);
    sum += bit ? p : 0.f;
  }
  #pragma unroll
  for (int off = 32; off; off >>= 1) sum += __shfl_xor(sum, off);
  if (lane == 0){ mm[i] = mmv; linv[i] = sum > 0.f ? 1.0f / sum : 0.f; }
}

// ----- fused PV (split-bf16, split-K): partial[kz] = P_range @ Wh ---------
// grid (2, 128, PV_SPLIT); reg double-buffered prefetch of V/mask/sd.
__global__ __launch_bounds__(256) void gat_pv(const u64* __restrict__ mask,
                                              const float* __restrict__ ss,
                                              const float* __restrict__ sd,
                                              const float* __restrict__ mm,
                                              const ushort_t* __restrict__ VThi,
                                              const ushort_t* __restrict__ VTlo,
                                              float* __restrict__ partial){
  __shared__ short8 BhiV[128 * 8];
  __shared__ short8 BloV[128 * 8];
  __shared__ short8 PhiV[32 * 8];
  __shared__ short8 PloV[32 * 8];
  char* Bhi = (char*)BhiV; char* Blo = (char*)BloV;
  char* Phi = (char*)PhiV; char* Plo = (char*)PloV;
  const int tid = threadIdx.x;
  const int i0 = blockIdx.y * 32;
  const int n0 = blockIdx.x * 128;
  const int kz = blockIdx.z;
  const int kbeg = kz * PV_KB, kend = kbeg + PV_KB;
  const int lane = tid & 63, wave = tid >> 6;
  const int wr = wave & 1, wc = wave >> 1;
  const int l15 = lane & 15, lhi = lane >> 4;
  const int pr = tid >> 3, pj8 = tid & 7;
  const int prow = i0 + pr;
  const float ssi = ss[prow];
  const float mmi = mm[prow];
  const u64* mrow = mask + (size_t)prow * 64;
  floatx4 acc[4] = {};

  short8 bhA[4], blA[4]; u64 wdA; floatx4 saA, sbA;
  short8 bhB[4], blB[4]; u64 wdB; floatx4 saB, sbB;

  auto LOADM = [&](int kb, short8* bh, short8* bl, u64& wd, floatx4& sa, floatx4& sb){
    #pragma unroll
    for (int q = 0; q < 4; ++q){
      int c = pr + q * 32;
      bh[q] = *(const short8*)(VThi + (size_t)(n0 + c) * GN + kb * 64 + pj8 * 8);
      bl[q] = *(const short8*)(VTlo + (size_t)(n0 + c) * GN + kb * 64 + pj8 * 8);
    }
    wd = mrow[kb];
    sa = *(const floatx4*)(sd + kb * 64 + pj8 * 8);
    sb = *(const floatx4*)(sd + kb * 64 + pj8 * 8 + 4);
  };

  auto PROCESS = [&](const short8* bh, const short8* bl, u64 wd, floatx4 sa, floatx4 sb){
    short8 pvh, pvl;
    const int shbase = pj8 * 8;
    #pragma unroll
    for (int e = 0; e < 8; ++e){
      float sv = (e < 4) ? sa[e] : sb[e - 4];
      float targ = ssi + sv;
      float lr = fmaxf(targ, 0.2f * targ);
      float p = exp2_(lr - mmi);
      uint bit = (uint)(wd >> (shbase + e)) & 1u;
      p = bit ? p : 0.0f;
      ushort_t h = f2bf(p);
      pvh[e] = (short)h;
      pvl[e] = (short)f2bf(p - bf2f(h));
    }
    const int swP = (pj8 * 16) ^ ((pr & 7) << 4);
    *(short8*)(Phi + pr * 128 + swP) = pvh;
    *(short8*)(Plo + pr * 128 + swP) = pvl;
    #pragma unroll
    for (int q = 0; q < 4; ++q){
      int c = pr + q * 32;
      const int swB = (pj8 * 16) ^ ((c & 7) << 4);
      *(short8*)(Bhi + c * 128 + swB) = bh[q];
      *(short8*)(Blo + c * 128 + swB) = bl[q];
    }
    __syncthreads();
    #pragma unroll
    for (int kt = 0; kt < 2; ++kt){
      int klb = (kt * 32 + lhi * 8) * 2;
      int rowA = wr * 16 + l15;
      int swA = klb ^ ((rowA & 7) << 4);
      short8 ah = *(const short8*)(Phi + rowA * 128 + swA);
      short8 al = *(const short8*)(Plo + rowA * 128 + swA);
      #pragma unroll
      for (int n = 0; n < 4; ++n){
        int rowB = wc * 64 + n * 16 + l15;
        int swB = klb ^ ((rowB & 7) << 4);
        short8 b_h = *(const short8*)(Bhi + rowB * 128 + swB);
        short8 b_l = *(const short8*)(Blo + rowB * 128 + swB);
        acc[n] = __builtin_amdgcn_mfma_f32_16x16x32_bf16(ah, b_h, acc[n], 0, 0, 0);
        acc[n] = __builtin_amdgcn_mfma_f32_16x16x32_bf16(ah, b_l, acc[n], 0, 0, 0);
        acc[n] = __builtin_amdgcn_mfma_f32_16x16x32_bf16(al, b_h, acc[n], 0, 0, 0);
      }
    }
    __syncthreads();
  };

  LOADM(kbeg, bhA, blA, wdA, saA, sbA);
  for (int kb = kbeg; kb < kend; kb += 2){
    LOADM(kb + 1, bhB, blB, wdB, saB, sbB);
    PROCESS(bhA, blA, wdA, saA, sbA);
    int k2 = (kb + 2 < kend) ? kb + 2 : kbeg;   // clamped redundant prefetch
    LOADM(k2, bhA, blA, wdA, saA, sbA);
    PROCESS(bhB, blB, wdB, saB, sbB);
  }

  float* pout = partial + (size_t)kz * GN * GH;
  #pragma unroll
  for (int n = 0; n < 4; ++n){
    int col = n0 + wc * 64 + n * 16 + l15;
    #pragma unroll
    for (int rr = 0; rr < 4; ++rr){
      pout[(size_t)(i0 + wr * 16 + lhi * 4 + rr) * GH + col] = acc[n][rr];
    }
  }
}

// -- combine split-K partials: scale by 1/l, ReLU, write outb, BN stats ----
__global__ __launch_bounds__(256) void combine_colpart(const float* __restrict__ partial,
                                                       const float* __restrict__ linv,
                                                       float* __restrict__ outb,
                                                       float* __restrict__ part,
                                                       float* __restrict__ partm2){
  const int c = threadIdx.x;
  const int b = blockIdx.x;
  float v[32];
  float s = 0.f;
  #pragma unroll
  for (int r = 0; r < 32; ++r){
    int row = b * 32 + r;
    size_t idx = (size_t)row * GH + c;
    float x = partial[idx];
    #pragma unroll
    for (int z = 1; z < PV_SPLIT; ++z) x += partial[(size_t)z * GN * GH + idx];
    x = fmaxf(x * linv[row], 0.0f);
    outb[idx] = x;
    v[r] = x; s += x;
  }
  const float mu = s * (1.0f / 32.0f);
  float m2 = 0.f;
  #pragma unroll
  for (int r = 0; r < 32; ++r){ float d = v[r] - mu; m2 += d * d; }
  part[b * GH + c] = s;
  partm2[b * GH + c] = m2;
}

// ---- combine block stats (Chan) in f64 -> per-column scale/bias ----------
__global__ __launch_bounds__(256) void colfin(const float* __restrict__ part,
                                              const float* __restrict__ partm2,
                                              const float* __restrict__ gamma,
                                              const float* __restrict__ beta,
                                              float* __restrict__ scale,
                                              float* __restrict__ bias){
  const int c = threadIdx.x;
  double S = 0.0;
  for (int b = 0; b < 128; ++b) S += (double)part[b * GH + c];
  const double mean = S * (1.0 / 4096.0);
  double M2 = 0.0;
  for (int b = 0; b < 128; ++b){
    double mb = (double)part[b * GH + c] * (1.0 / 32.0);
    double d = mb - mean;
    M2 += (double)partm2[b * GH + c] + 32.0 * d * d;
  }
  const double var = M2 * (1.0 / 4096.0);
  float sc = gamma[c] * (float)(1.0 / sqrt(var + 1e-5));
  scale[c] = sc;
  bias[c] = beta[c] - (float)mean * sc;
}

// ------------------- apply BN: h*scale + bias -> f32 ----------------------
__global__ __launch_bounds__(256) void bnapply(const float* __restrict__ outb,
                                               const float* __restrict__ scale,
                                               const float* __restrict__ bias,
                                               float* __restrict__ dst){
  const int base = (blockIdx.x * 256 + threadIdx.x) * 4;
  const int c = base & (GH - 1);
  floatx4 v = *(const floatx4*)(outb + base);
  floatx4 s = *(const floatx4*)(scale + c);
  floatx4 b = *(const floatx4*)(bias + c);
  #pragma unroll
  for (int e = 0; e < 4; ++e) v[e] = v[e] * s[e] + b[e];
  *(floatx4*)(dst + base) = v;
}

extern "C" void kernel_launch(void* const* d_in, const int* in_sizes, int n_in,
                              void* d_out, int out_size, void* d_ws, size_t ws_size,
                              hipStream_t stream) {
  const float* x      = (const float*)d_in[0];
  const int*   adj    = (const int*)d_in[1];
  const float* W1     = (const float*)d_in[2];
  const float* a1s    = (const float*)d_in[3];
  const float* a1d    = (const float*)d_in[4];
  const float* g1     = (const float*)d_in[5];
  const float* b1     = (const float*)d_in[6];
  const float* W2     = (const float*)d_in[7];
  const float* a2s    = (const float*)d_in[8];
  const float* a2d    = (const float*)d_in[9];
  const float* g2     = (const float*)d_in[10];
  const float* b2     = (const float*)d_in[11];

  char* w = (char*)d_ws;
  auto alloc = [&](size_t bytes){ void* p = (void*)w; w += (bytes + 255) & ~(size_t)255; return p; };
  u64*      mask   = (u64*)alloc((size_t)GN * 64 * 8);          // 2 MB
  ushort_t* W1Th   = (ushort_t*)alloc((size_t)GH * 512 * 2);    // 256 KB
  ushort_t* W1Tl   = (ushort_t*)alloc((size_t)GH * 512 * 2);    // 256 KB
  ushort_t* W2Th   = (ushort_t*)alloc((size_t)GH * GH * 2);     // 128 KB
  ushort_t* W2Tl   = (ushort_t*)alloc((size_t)GH * GH * 2);     // 128 KB
  float*    Whf    = (float*)alloc((size_t)GN * GH * 4);        // 4 MB
  ushort_t* WTh    = (ushort_t*)alloc((size_t)GH * GN * 2);     // 2 MB
  ushort_t* WTl    = (ushort_t*)alloc((size_t)GH * GN * 2);     // 2 MB
  float*    hf     = (float*)alloc((size_t)GN * GH * 4);        // 4 MB
  float*    outb   = (float*)alloc((size_t)GN * GH * 4);        // 4 MB
  float*    partial= (float*)alloc((size_t)PV_SPLIT * GN * GH * 4); // 16 MB
  float*    ssb    = (float*)alloc(GN * 4);
  float*    sdb    = (float*)alloc(GN * 4);
  float*    mmb    = (float*)alloc(GN * 4);
  float*    linvb  = (float*)alloc(GN * 4);
  float*    part   = (float*)alloc(128 * GH * 4);
  float*    partm2 = (float*)alloc(128 * GH * 4);
  float*    scale  = (float*)alloc(GH * 4);
  float*    bias   = (float*)alloc(GH * 4);

  pack_mask<<<1024, 256, 0, stream>>>(adj, mask);
  transpose_split<<<(512/32)*(GH/32), 256, 0, stream>>>(W1, W1Th, W1Tl, 512, GH);
  transpose_split<<<(GH/32)*(GH/32), 256, 0, stream>>>(W2, W2Th, W2Tl, GH, GH);

  // ---- layer 1 ----
  gemm_split<<<dim3(4, 128), 256, 0, stream>>>(x, W1Th, W1Tl, Whf, 512);
  skernel<<<1024, 256, 0, stream>>>(Whf, a1s, a1d, ssb, sdb);
  transpose_split<<<(GN/32)*(GH/32), 256, 0, stream>>>(Whf, WTh, WTl, GN, GH);
  rowstats<<<1024, 256, 0, stream>>>(mask, ssb, sdb, mmb, linvb);
  gat_pv<<<dim3(2, 128, PV_SPLIT), 256, 0, stream>>>(mask, ssb, sdb, mmb, WTh, WTl, partial);
  combine_colpart<<<128, 256, 0, stream>>>(partial, linvb, outb, part, partm2);
  colfin<<<1, 256, 0, stream>>>(part, partm2, g1, b1, scale, bias);
  bnapply<<<1024, 256, 0, stream>>>(outb, scale, bias, hf);

  // ---- layer 2 ----
  gemm_split<<<dim3(4, 128), 256, 0, stream>>>(hf, W2Th, W2Tl, Whf, 256);
  skernel<<<1024, 256, 0, stream>>>(Whf, a2s, a2d, ssb, sdb);
  transpose_split<<<(GN/32)*(GH/32), 256, 0, stream>>>(Whf, WTh, WTl, GN, GH);
  rowstats<<<1024, 256, 0, stream>>>(mask, ssb, sdb, mmb, linvb);
  gat_pv<<<dim3(2, 128, PV_SPLIT), 256, 0, stream>>>(mask, ssb, sdb, mmb, WTh, WTl, partial);
  combine_colpart<<<128, 256, 0, stream>>>(partial, linvb, outb, part, partm2);
  colfin<<<1, 256, 0, stream>>>(part, partm2, g2, b2, scale, bias);
  bnapply<<<1024, 256, 0, stream>>>(outb, scale, bias, (float*)d_out);
}

// Round 5
// 172.110 us; speedup vs baseline: 1.6784x; 1.2840x over previous
//
#include <hip/hip_runtime.h>

#define LOG2E 1.4426950408889634f

typedef unsigned long long u64;
typedef unsigned int uint;
typedef unsigned short ushort_t;
typedef __attribute__((ext_vector_type(8))) short short8;
typedef __attribute__((ext_vector_type(4))) float floatx4;
typedef __attribute__((ext_vector_type(4))) unsigned short ushort4v;

#define GN 4096
#define GH 256
#define KZ 8
#define KSTEPS 16   // K-steps of 32 neighbors per block: KZ*KSTEPS*32 = 4096

__device__ __forceinline__ ushort_t f2bf(float f){
  uint u = __float_as_uint(f);
  u += 0x7FFFu + ((u >> 16) & 1u);
  return (ushort_t)(u >> 16);
}
__device__ __forceinline__ float bf2f(ushort_t h){
  return __uint_as_float(((uint)h) << 16);
}
__device__ __forceinline__ float exp2_(float x){
#if __has_builtin(__builtin_amdgcn_exp2f)
  return __builtin_amdgcn_exp2f(x);
#else
  return exp2f(x);
#endif
}

// ---------------- adj (int32 0/1) -> bitmask u64[4096][64] ----------------
__global__ __launch_bounds__(256) void pack_mask(const int* __restrict__ adj,
                                                 u64* __restrict__ mask){
  const int lane = threadIdx.x & 63;
  const int i = blockIdx.x * 4 + (threadIdx.x >> 6);
  const int* row = adj + (size_t)i * GN;
  for (int w = 0; w < 64; ++w){
    int v = row[w * 64 + lane];
    u64 b = __ballot(v > 0);
    if (lane == 0) mask[(size_t)i * 64 + w] = b;
  }
}

// ---- transpose f32 [R][C] -> split bf16 hi/lo planes [C][R] (for W) ------
__global__ __launch_bounds__(256) void transpose_split(const float* __restrict__ in,
                                                       ushort_t* __restrict__ hi,
                                                       ushort_t* __restrict__ lo,
                                                       int R, int C){
  __shared__ ushort_t th[32][33];
  __shared__ ushort_t tl[32][33];
  const int ctiles = C >> 5;
  const int bx = blockIdx.x % ctiles;
  const int by = blockIdx.x / ctiles;
  const int i0 = by * 32, j0 = bx * 32;
  const int r = threadIdx.x >> 3, c4 = (threadIdx.x & 7) * 4;
  floatx4 v = *(const floatx4*)(in + (size_t)(i0 + r) * C + j0 + c4);
  #pragma unroll
  for (int e = 0; e < 4; ++e){
    ushort_t h = f2bf(v[e]);
    th[r][c4 + e] = h;
    tl[r][c4 + e] = f2bf(v[e] - bf2f(h));
  }
  __syncthreads();
  ushort4v oh, ol;
  #pragma unroll
  for (int e = 0; e < 4; ++e){ oh[e] = th[c4 + e][r]; ol[e] = tl[c4 + e][r]; }
  *(ushort4v*)(hi + (size_t)(j0 + r) * R + i0 + c4) = oh;
  *(ushort4v*)(lo + (size_t)(j0 + r) * R + i0 + c4) = ol;
}

// ---- transpose f32 [R][C] -> bf16 hi plane only [C][R] (for V) -----------
__global__ __launch_bounds__(256) void transpose_hi(const float* __restrict__ in,
                                                    ushort_t* __restrict__ hi,
                                                    int R, int C){
  __shared__ ushort_t th[32][33];
  const int ctiles = C >> 5;
  const int bx = blockIdx.x % ctiles;
  const int by = blockIdx.x / ctiles;
  const int i0 = by * 32, j0 = bx * 32;
  const int r = threadIdx.x >> 3, c4 = (threadIdx.x & 7) * 4;
  floatx4 v = *(const floatx4*)(in + (size_t)(i0 + r) * C + j0 + c4);
  #pragma unroll
  for (int e = 0; e < 4; ++e) th[r][c4 + e] = f2bf(v[e]);
  __syncthreads();
  ushort4v oh;
  #pragma unroll
  for (int e = 0; e < 4; ++e) oh[e] = th[c4 + e][r];
  *(ushort4v*)(hi + (size_t)(j0 + r) * R + i0 + c4) = oh;
}

// --- split-bf16 GEMM (~f32): Cf[M][256] = A_f32[M][K] @ BT^T --------------
__global__ __launch_bounds__(256) void gemm_split(const float* __restrict__ A,
                                                  const ushort_t* __restrict__ BThi,
                                                  const ushort_t* __restrict__ BTlo,
                                                  float* __restrict__ Cf, int K){
  __shared__ short8 AhiV[32 * 8];
  __shared__ short8 AloV[32 * 8];
  __shared__ short8 BhiV[64 * 8];
  __shared__ short8 BloV[64 * 8];
  char* Ahi = (char*)AhiV; char* Alo = (char*)AloV;
  char* Bhi = (char*)BhiV; char* Blo = (char*)BloV;
  const int tid = threadIdx.x;
  const int i0 = blockIdx.y * 32, n0 = blockIdx.x * 64;
  const int lane = tid & 63, wave = tid >> 6;
  const int wr = wave & 1, wc = wave >> 1;
  const int l15 = lane & 15, lhi = lane >> 4;
  const int rs = tid >> 3, ch = tid & 7;
  floatx4 acc[2] = {};
  for (int kb = 0; kb < K; kb += 64){
    {
      int r = rs;
      floatx4 f0 = *(const floatx4*)(A + (size_t)(i0 + r) * K + kb + ch * 8);
      floatx4 f1 = *(const floatx4*)(A + (size_t)(i0 + r) * K + kb + ch * 8 + 4);
      short8 ah, al;
      #pragma unroll
      for (int e = 0; e < 4; ++e){
        ushort_t h0 = f2bf(f0[e]); ah[e] = (short)h0; al[e] = (short)f2bf(f0[e] - bf2f(h0));
        ushort_t h1 = f2bf(f1[e]); ah[e+4] = (short)h1; al[e+4] = (short)f2bf(f1[e] - bf2f(h1));
      }
      const int sw = (ch * 16) ^ ((r & 7) << 4);
      *(short8*)(Ahi + r * 128 + sw) = ah;
      *(short8*)(Alo + r * 128 + sw) = al;
      #pragma unroll
      for (int q = 0; q < 2; ++q){
        int rb = rs + q * 32;
        const int swb = (ch * 16) ^ ((rb & 7) << 4);
        short8 bh = *(const short8*)(BThi + (size_t)(n0 + rb) * K + kb + ch * 8);
        short8 bl = *(const short8*)(BTlo + (size_t)(n0 + rb) * K + kb + ch * 8);
        *(short8*)(Bhi + rb * 128 + swb) = bh;
        *(short8*)(Blo + rb * 128 + swb) = bl;
      }
    }
    __syncthreads();
    #pragma unroll
    for (int kt = 0; kt < 2; ++kt){
      int klb = (kt * 32 + lhi * 8) * 2;
      int rowA = wr * 16 + l15;
      int swA = klb ^ ((rowA & 7) << 4);
      short8 ah = *(const short8*)(Ahi + rowA * 128 + swA);
      short8 al = *(const short8*)(Alo + rowA * 128 + swA);
      #pragma unroll
      for (int n = 0; n < 2; ++n){
        int rowB = wc * 32 + n * 16 + l15;
        int swB = klb ^ ((rowB & 7) << 4);
        short8 bh = *(const short8*)(Bhi + rowB * 128 + swB);
        short8 bl = *(const short8*)(Blo + rowB * 128 + swB);
        acc[n] = __builtin_amdgcn_mfma_f32_16x16x32_bf16(ah, bh, acc[n], 0, 0, 0);
        acc[n] = __builtin_amdgcn_mfma_f32_16x16x32_bf16(ah, bl, acc[n], 0, 0, 0);
        acc[n] = __builtin_amdgcn_mfma_f32_16x16x32_bf16(al, bh, acc[n], 0, 0, 0);
      }
    }
    __syncthreads();
  }
  #pragma unroll
  for (int rr = 0; rr < 4; ++rr){
    int row = i0 + wr * 16 + lhi * 4 + rr;
    #pragma unroll
    for (int n = 0; n < 2; ++n){
      int col = n0 + wc * 32 + n * 16 + l15;
      Cf[(size_t)row * GH + col] = acc[n][rr];
    }
  }
}

// ---------- per-row s_src, s_dst (pre-scaled by log2e) from f32 Wh --------
__global__ __launch_bounds__(256) void skernel(const float* __restrict__ Whf,
                                               const float* __restrict__ asrc,
                                               const float* __restrict__ adst,
                                               float* __restrict__ ss,
                                               float* __restrict__ sd){
  const int lane = threadIdx.x & 63;
  const int i = blockIdx.x * 4 + (threadIdx.x >> 6);
  floatx4 w = *(const floatx4*)(Whf + (size_t)i * GH + lane * 4);
  floatx4 s4 = *(const floatx4*)(asrc + lane * 4);
  floatx4 d4 = *(const floatx4*)(adst + lane * 4);
  float s = 0.f, d = 0.f;
  #pragma unroll
  for (int e = 0; e < 4; ++e){
    s += w[e] * s4[e]; d += w[e] * d4[e];
  }
  #pragma unroll
  for (int off = 32; off; off >>= 1){
    s += __shfl_xor(s, off);
    d += __shfl_xor(d, off);
  }
  if (lane == 0){ ss[i] = s * LOG2E; sd[i] = d * LOG2E; }
}

// --------- per-row masked max (m) and inv exp-sum (1/l); sd cached in LDS --
__global__ __launch_bounds__(256) void rowstats(const u64* __restrict__ mask,
                                                const float* __restrict__ ss,
                                                const float* __restrict__ sd,
                                                float* __restrict__ mm,
                                                float* __restrict__ linv){
  __shared__ float sdl[GN];
  const int tid = threadIdx.x;
  #pragma unroll
  for (int q = 0; q < 4; ++q){
    int idx = (q * 256 + tid) * 4;
    *(floatx4*)(sdl + idx) = *(const floatx4*)(sd + idx);
  }
  __syncthreads();
  const int lane = tid & 63;
  const int i = blockIdx.x * 4 + (tid >> 6);
  const u64* mrow = mask + (size_t)i * 64;
  float mx = -3.0e38f;
  for (int it = 0; it < 64; ++it){
    u64 word = mrow[it];
    float v = sdl[it * 64 + lane];
    uint bit = (uint)(word >> lane) & 1u;
    mx = fmaxf(mx, bit ? v : -3.0e38f);
  }
  #pragma unroll
  for (int off = 32; off; off >>= 1) mx = fmaxf(mx, __shfl_xor(mx, off));
  const float ssi = ss[i];
  float targ = ssi + mx;
  float mmv = fmaxf(targ, 0.2f * targ);
  float sum = 0.f;
  for (int it = 0; it < 64; ++it){
    u64 word = mrow[it];
    float v = sdl[it * 64 + lane];
    uint bit = (uint)(word >> lane) & 1u;
    float a = ssi + v;
    float lr = fmaxf(a, 0.2f * a);
    float p = exp2_(lr - mmv);
    sum += bit ? p : 0.f;
  }
  #pragma unroll
  for (int off = 32; off; off >>= 1) sum += __shfl_xor(sum, off);
  if (lane == 0){ mm[i] = mmv; linv[i] = sum > 0.f ? 1.0f / sum : 0.f; }
}

// ----- fused PV: in-register P (MFMA A-layout), B-only LDS, split-K -------
// block = 128 thr (2 waves), tile 64 rows x 256 cols, K-chunk = KSTEPS*32.
// LDS: double-buffered V tile [256 cols][32 k] bf16, 80B row stride.
__global__ __launch_bounds__(128, 2) void gat_pv(const u64* __restrict__ mask,
                                                 const float* __restrict__ ss,
                                                 const float* __restrict__ sd,
                                                 const float* __restrict__ mm,
                                                 const ushort_t* __restrict__ VTh,
                                                 float* __restrict__ partial){
  __shared__ char Blds[2][20480];
  const int tid = threadIdx.x;
  const int lane = tid & 63, w = tid >> 6;
  const int l15 = lane & 15, lhi = lane >> 4;
  const int i0 = blockIdx.x * 64;
  const int kz = blockIdx.y;
  const int ch = tid & 3, c0 = tid >> 2;   // staging: 16B chunk, col base

  const int row0 = i0 + w * 32 + l15;
  const int row1 = row0 + 16;
  const float ss0 = ss[row0], mm0 = mm[row0];
  const float ss1 = ss[row1], mm1 = mm[row1];
  const u64* mr0 = mask + (size_t)row0 * 64;
  const u64* mr1 = mask + (size_t)row1 * 64;

  floatx4 acc[2][16] = {};
  short8 g[8];

  auto GLOAD = [&](int kb){
    const int kbase = (kz * KSTEPS + kb) * 32;
    #pragma unroll
    for (int i = 0; i < 8; ++i){
      int c = c0 + 32 * i;
      g[i] = *(const short8*)(VTh + (size_t)c * GN + kbase + ch * 8);
    }
  };
  auto SWRITE = [&](int buf){
    #pragma unroll
    for (int i = 0; i < 8; ++i){
      int c = c0 + 32 * i;
      *(short8*)(Blds[buf] + c * 80 + ch * 16) = g[i];
    }
  };

  GLOAD(0); SWRITE(0); __syncthreads();

  for (int kb = 0; kb < KSTEPS; ++kb){
    if (kb + 1 < KSTEPS) GLOAD(kb + 1);

    const int kstep = kz * KSTEPS + kb;
    const int kbase = kstep * 32;
    floatx4 s0 = *(const floatx4*)(sd + kbase + lhi * 8);
    floatx4 s1 = *(const floatx4*)(sd + kbase + lhi * 8 + 4);
    const int sh = ((kstep & 1) << 5) + lhi * 8;
    uint bits0 = (uint)(mr0[kstep >> 1] >> sh) & 0xffu;
    uint bits1 = (uint)(mr1[kstep >> 1] >> sh) & 0xffu;
    short8 a0, a1;
    #pragma unroll
    for (int e = 0; e < 8; ++e){
      float sv = (e < 4) ? s0[e] : s1[e - 4];
      float t0 = ss0 + sv, t1 = ss1 + sv;
      float lr0 = fmaxf(t0, 0.2f * t0), lr1 = fmaxf(t1, 0.2f * t1);
      float p0 = exp2_(lr0 - mm0), p1 = exp2_(lr1 - mm1);
      p0 = ((bits0 >> e) & 1u) ? p0 : 0.0f;
      p1 = ((bits1 >> e) & 1u) ? p1 : 0.0f;
      a0[e] = (short)f2bf(p0);
      a1[e] = (short)f2bf(p1);
    }

    const char* B = Blds[kb & 1];
    #pragma unroll
    for (int n = 0; n < 16; ++n){
      short8 b = *(const short8*)(B + (n * 16 + l15) * 80 + lhi * 16);
      acc[0][n] = __builtin_amdgcn_mfma_f32_16x16x32_bf16(a0, b, acc[0][n], 0, 0, 0);
      acc[1][n] = __builtin_amdgcn_mfma_f32_16x16x32_bf16(a1, b, acc[1][n], 0, 0, 0);
    }

    if (kb + 1 < KSTEPS){
      SWRITE((kb + 1) & 1);
      __syncthreads();
    }
  }

  float* pout = partial + (size_t)kz * GN * GH;
  #pragma unroll
  for (int m = 0; m < 2; ++m){
    int rbase = i0 + w * 32 + m * 16 + lhi * 4;
    #pragma unroll
    for (int n = 0; n < 16; ++n){
      int col = n * 16 + l15;
      #pragma unroll
      for (int rr = 0; rr < 4; ++rr)
        pout[(size_t)(rbase + rr) * GH + col] = acc[m][n][rr];
    }
  }
}

// -- combine split-K partials: scale by 1/l, ReLU, write outb, BN stats ----
__global__ __launch_bounds__(256) void combine_colpart(const float* __restrict__ partial,
                                                       const float* __restrict__ linv,
                                                       float* __restrict__ outb,
                                                       float* __restrict__ part,
                                                       float* __restrict__ partm2){
  const int c = threadIdx.x;
  const int b = blockIdx.x;
  float v[32];
  float s = 0.f;
  #pragma unroll
  for (int r = 0; r < 32; ++r){
    int row = b * 32 + r;
    size_t idx = (size_t)row * GH + c;
    float x = partial[idx];
    #pragma unroll
    for (int z = 1; z < KZ; ++z) x += partial[(size_t)z * GN * GH + idx];
    x = fmaxf(x * linv[row], 0.0f);
    outb[idx] = x;
    v[r] = x; s += x;
  }
  const float mu = s * (1.0f / 32.0f);
  float m2 = 0.f;
  #pragma unroll
  for (int r = 0; r < 32; ++r){ float d = v[r] - mu; m2 += d * d; }
  part[b * GH + c] = s;
  partm2[b * GH + c] = m2;
}

// ---- combine block stats (Chan) in f64 -> per-column scale/bias ----------
__global__ __launch_bounds__(256) void colfin(const float* __restrict__ part,
                                              const float* __restrict__ partm2,
                                              const float* __restrict__ gamma,
                                              const float* __restrict__ beta,
                                              float* __restrict__ scale,
                                              float* __restrict__ bias){
  const int c = threadIdx.x;
  double S = 0.0;
  for (int b = 0; b < 128; ++b) S += (double)part[b * GH + c];
  const double mean = S * (1.0 / 4096.0);
  double M2 = 0.0;
  for (int b = 0; b < 128; ++b){
    double mb = (double)part[b * GH + c] * (1.0 / 32.0);
    double d = mb - mean;
    M2 += (double)partm2[b * GH + c] + 32.0 * d * d;
  }
  const double var = M2 * (1.0 / 4096.0);
  float sc = gamma[c] * (float)(1.0 / sqrt(var + 1e-5));
  scale[c] = sc;
  bias[c] = beta[c] - (float)mean * sc;
}

// ------------------- apply BN: h*scale + bias -> f32 ----------------------
__global__ __launch_bounds__(256) void bnapply(const float* __restrict__ outb,
                                               const float* __restrict__ scale,
                                               const float* __restrict__ bias,
                                               float* __restrict__ dst){
  const int base = (blockIdx.x * 256 + threadIdx.x) * 4;
  const int c = base & (GH - 1);
  floatx4 v = *(const floatx4*)(outb + base);
  floatx4 s = *(const floatx4*)(scale + c);
  floatx4 b = *(const floatx4*)(bias + c);
  #pragma unroll
  for (int e = 0; e < 4; ++e) v[e] = v[e] * s[e] + b[e];
  *(floatx4*)(dst + base) = v;
}

extern "C" void kernel_launch(void* const* d_in, const int* in_sizes, int n_in,
                              void* d_out, int out_size, void* d_ws, size_t ws_size,
                              hipStream_t stream) {
  const float* x      = (const float*)d_in[0];
  const int*   adj    = (const int*)d_in[1];
  const float* W1     = (const float*)d_in[2];
  const float* a1s    = (const float*)d_in[3];
  const float* a1d    = (const float*)d_in[4];
  const float* g1     = (const float*)d_in[5];
  const float* b1     = (const float*)d_in[6];
  const float* W2     = (const float*)d_in[7];
  const float* a2s    = (const float*)d_in[8];
  const float* a2d    = (const float*)d_in[9];
  const float* g2     = (const float*)d_in[10];
  const float* b2     = (const float*)d_in[11];

  char* w = (char*)d_ws;
  auto alloc = [&](size_t bytes){ void* p = (void*)w; w += (bytes + 255) & ~(size_t)255; return p; };
  u64*      mask   = (u64*)alloc((size_t)GN * 64 * 8);          // 2 MB
  ushort_t* W1Th   = (ushort_t*)alloc((size_t)GH * 512 * 2);
  ushort_t* W1Tl   = (ushort_t*)alloc((size_t)GH * 512 * 2);
  ushort_t* W2Th   = (ushort_t*)alloc((size_t)GH * GH * 2);
  ushort_t* W2Tl   = (ushort_t*)alloc((size_t)GH * GH * 2);
  float*    Whf    = (float*)alloc((size_t)GN * GH * 4);        // 4 MB
  ushort_t* VThb   = (ushort_t*)alloc((size_t)GH * GN * 2);     // 2 MB
  float*    hf     = (float*)alloc((size_t)GN * GH * 4);        // 4 MB
  float*    outb   = (float*)alloc((size_t)GN * GH * 4);        // 4 MB
  float*    partial= (float*)alloc((size_t)KZ * GN * GH * 4);   // 32 MB
  float*    ssb    = (float*)alloc(GN * 4);
  float*    sdb    = (float*)alloc(GN * 4);
  float*    mmb    = (float*)alloc(GN * 4);
  float*    linvb  = (float*)alloc(GN * 4);
  float*    part   = (float*)alloc(128 * GH * 4);
  float*    partm2 = (float*)alloc(128 * GH * 4);
  float*    scale  = (float*)alloc(GH * 4);
  float*    bias   = (float*)alloc(GH * 4);

  pack_mask<<<1024, 256, 0, stream>>>(adj, mask);
  transpose_split<<<(512/32)*(GH/32), 256, 0, stream>>>(W1, W1Th, W1Tl, 512, GH);
  transpose_split<<<(GH/32)*(GH/32), 256, 0, stream>>>(W2, W2Th, W2Tl, GH, GH);

  // ---- layer 1 ----
  gemm_split<<<dim3(4, 128), 256, 0, stream>>>(x, W1Th, W1Tl, Whf, 512);
  skernel<<<1024, 256, 0, stream>>>(Whf, a1s, a1d, ssb, sdb);
  transpose_hi<<<(GN/32)*(GH/32), 256, 0, stream>>>(Whf, VThb, GN, GH);
  rowstats<<<1024, 256, 0, stream>>>(mask, ssb, sdb, mmb, linvb);
  gat_pv<<<dim3(64, KZ), 128, 0, stream>>>(mask, ssb, sdb, mmb, VThb, partial);
  combine_colpart<<<128, 256, 0, stream>>>(partial, linvb, outb, part, partm2);
  colfin<<<1, 256, 0, stream>>>(part, partm2, g1, b1, scale, bias);
  bnapply<<<1024, 256, 0, stream>>>(outb, scale, bias, hf);

  // ---- layer 2 ----
  gemm_split<<<dim3(4, 128), 256, 0, stream>>>(hf, W2Th, W2Tl, Whf, 256);
  skernel<<<1024, 256, 0, stream>>>(Whf, a2s, a2d, ssb, sdb);
  transpose_hi<<<(GN/32)*(GH/32), 256, 0, stream>>>(Whf, VThb, GN, GH);
  rowstats<<<1024, 256, 0, stream>>>(mask, ssb, sdb, mmb, linvb);
  gat_pv<<<dim3(64, KZ), 128, 0, stream>>>(mask, ssb, sdb, mmb, VThb, partial);
  combine_colpart<<<128, 256, 0, stream>>>(partial, linvb, outb, part, partm2);
  colfin<<<1, 256, 0, stream>>>(part, partm2, g2, b2, scale, bias);
  bnapply<<<1024, 256, 0, stream>>>(outb, scale, bias, (float*)d_out);
}

// Round 6
// 164.616 us; speedup vs baseline: 1.7548x; 1.0455x over previous
//
#include <hip/hip_runtime.h>

#define LOG2E 1.4426950408889634f

typedef unsigned long long u64;
typedef unsigned int uint;
typedef unsigned short ushort_t;
typedef __attribute__((ext_vector_type(8))) short short8;
typedef __attribute__((ext_vector_type(4))) float floatx4;
typedef __attribute__((ext_vector_type(4))) int intx4;
typedef __attribute__((ext_vector_type(4))) unsigned short ushort4v;

#define GN 4096
#define GH 256
#define KZ 8
#define KSTEPS 16   // K-steps of 32 neighbors per block: KZ*KSTEPS*32 = 4096

__device__ __forceinline__ ushort_t f2bf(float f){
  uint u = __float_as_uint(f);
  u += 0x7FFFu + ((u >> 16) & 1u);
  return (ushort_t)(u >> 16);
}
__device__ __forceinline__ float bf2f(ushort_t h){
  return __uint_as_float(((uint)h) << 16);
}
__device__ __forceinline__ float exp2_(float x){
#if __has_builtin(__builtin_amdgcn_exp2f)
  return __builtin_amdgcn_exp2f(x);
#else
  return exp2f(x);
#endif
}

// ------- adj (int32 0/1) -> bitmask u64[4096][64], two-phase coalesced ----
// Phase 1: coalesced int4 loads, nibble per int4 into LDS.
// Phase 2: bit-compress 16 nibble-bytes -> one u64 mask word.
__global__ __launch_bounds__(256) void pack_mask(const int* __restrict__ adj,
                                                 u64* __restrict__ mask){
  __shared__ unsigned char nib[2][1024];   // 2 rows x 1024 nibble-bytes
  const int t = threadIdx.x;
  const int r0 = blockIdx.x * 2;
  const int* base = adj + (size_t)r0 * GN;
  #pragma unroll
  for (int i = 0; i < 8; ++i){
    int c = i * 256 + t;                    // int4 index within 2 rows (0..2047)
    intx4 v = *(const intx4*)(base + c * 4);
    uint n = (uint)(v[0] > 0) | ((uint)(v[1] > 0) << 1) |
             ((uint)(v[2] > 0) << 2) | ((uint)(v[3] > 0) << 3);
    nib[c >> 10][c & 1023] = (unsigned char)n;
  }
  __syncthreads();
  if (t < 128){
    int r = t >> 6, wi = t & 63;
    const u64* p = (const u64*)nib[r];
    u64 x0 = p[wi * 2], x1 = p[wi * 2 + 1];
    auto comp = [](u64 x)->u64{
      x = (x | (x >> 4))  & 0x00FF00FF00FF00FFULL;
      x = (x | (x >> 8))  & 0x0000FFFF0000FFFFULL;
      x = (x | (x >> 16)) & 0x00000000FFFFFFFFULL;
      return x;
    };
    mask[(size_t)(r0 + r) * 64 + wi] = comp(x0) | (comp(x1) << 32);
  }
}

// ---- transpose f32 [R][C] -> split bf16 hi/lo planes [C][R] (for W) ------
__global__ __launch_bounds__(256) void transpose_split(const float* __restrict__ in,
                                                       ushort_t* __restrict__ hi,
                                                       ushort_t* __restrict__ lo,
                                                       int R, int C){
  __shared__ ushort_t th[32][33];
  __shared__ ushort_t tl[32][33];
  const int ctiles = C >> 5;
  const int bx = blockIdx.x % ctiles;
  const int by = blockIdx.x / ctiles;
  const int i0 = by * 32, j0 = bx * 32;
  const int r = threadIdx.x >> 3, c4 = (threadIdx.x & 7) * 4;
  floatx4 v = *(const floatx4*)(in + (size_t)(i0 + r) * C + j0 + c4);
  #pragma unroll
  for (int e = 0; e < 4; ++e){
    ushort_t h = f2bf(v[e]);
    th[r][c4 + e] = h;
    tl[r][c4 + e] = f2bf(v[e] - bf2f(h));
  }
  __syncthreads();
  ushort4v oh, ol;
  #pragma unroll
  for (int e = 0; e < 4; ++e){ oh[e] = th[c4 + e][r]; ol[e] = tl[c4 + e][r]; }
  *(ushort4v*)(hi + (size_t)(j0 + r) * R + i0 + c4) = oh;
  *(ushort4v*)(lo + (size_t)(j0 + r) * R + i0 + c4) = ol;
}

// ---- transpose f32 [R][C] -> bf16 hi plane only [C][R] (for V) -----------
__global__ __launch_bounds__(256) void transpose_hi(const float* __restrict__ in,
                                                    ushort_t* __restrict__ hi,
                                                    int R, int C){
  __shared__ ushort_t th[32][33];
  const int ctiles = C >> 5;
  const int bx = blockIdx.x % ctiles;
  const int by = blockIdx.x / ctiles;
  const int i0 = by * 32, j0 = bx * 32;
  const int r = threadIdx.x >> 3, c4 = (threadIdx.x & 7) * 4;
  floatx4 v = *(const floatx4*)(in + (size_t)(i0 + r) * C + j0 + c4);
  #pragma unroll
  for (int e = 0; e < 4; ++e) th[r][c4 + e] = f2bf(v[e]);
  __syncthreads();
  ushort4v oh;
  #pragma unroll
  for (int e = 0; e < 4; ++e) oh[e] = th[c4 + e][r];
  *(ushort4v*)(hi + (size_t)(j0 + r) * R + i0 + c4) = oh;
}

// --- split-bf16 GEMM (~f32): Cf[M][256] = A_f32[M][K] @ BT^T --------------
__global__ __launch_bounds__(256) void gemm_split(const float* __restrict__ A,
                                                  const ushort_t* __restrict__ BThi,
                                                  const ushort_t* __restrict__ BTlo,
                                                  float* __restrict__ Cf, int K){
  __shared__ short8 AhiV[32 * 8];
  __shared__ short8 AloV[32 * 8];
  __shared__ short8 BhiV[64 * 8];
  __shared__ short8 BloV[64 * 8];
  char* Ahi = (char*)AhiV; char* Alo = (char*)AloV;
  char* Bhi = (char*)BhiV; char* Blo = (char*)BloV;
  const int tid = threadIdx.x;
  const int i0 = blockIdx.y * 32, n0 = blockIdx.x * 64;
  const int lane = tid & 63, wave = tid >> 6;
  const int wr = wave & 1, wc = wave >> 1;
  const int l15 = lane & 15, lhi = lane >> 4;
  const int rs = tid >> 3, ch = tid & 7;
  floatx4 acc[2] = {};
  for (int kb = 0; kb < K; kb += 64){
    {
      int r = rs;
      floatx4 f0 = *(const floatx4*)(A + (size_t)(i0 + r) * K + kb + ch * 8);
      floatx4 f1 = *(const floatx4*)(A + (size_t)(i0 + r) * K + kb + ch * 8 + 4);
      short8 ah, al;
      #pragma unroll
      for (int e = 0; e < 4; ++e){
        ushort_t h0 = f2bf(f0[e]); ah[e] = (short)h0; al[e] = (short)f2bf(f0[e] - bf2f(h0));
        ushort_t h1 = f2bf(f1[e]); ah[e+4] = (short)h1; al[e+4] = (short)f2bf(f1[e] - bf2f(h1));
      }
      const int sw = (ch * 16) ^ ((r & 7) << 4);
      *(short8*)(Ahi + r * 128 + sw) = ah;
      *(short8*)(Alo + r * 128 + sw) = al;
      #pragma unroll
      for (int q = 0; q < 2; ++q){
        int rb = rs + q * 32;
        const int swb = (ch * 16) ^ ((rb & 7) << 4);
        short8 bh = *(const short8*)(BThi + (size_t)(n0 + rb) * K + kb + ch * 8);
        short8 bl = *(const short8*)(BTlo + (size_t)(n0 + rb) * K + kb + ch * 8);
        *(short8*)(Bhi + rb * 128 + swb) = bh;
        *(short8*)(Blo + rb * 128 + swb) = bl;
      }
    }
    __syncthreads();
    #pragma unroll
    for (int kt = 0; kt < 2; ++kt){
      int klb = (kt * 32 + lhi * 8) * 2;
      int rowA = wr * 16 + l15;
      int swA = klb ^ ((rowA & 7) << 4);
      short8 ah = *(const short8*)(Ahi + rowA * 128 + swA);
      short8 al = *(const short8*)(Alo + rowA * 128 + swA);
      #pragma unroll
      for (int n = 0; n < 2; ++n){
        int rowB = wc * 32 + n * 16 + l15;
        int swB = klb ^ ((rowB & 7) << 4);
        short8 bh = *(const short8*)(Bhi + rowB * 128 + swB);
        short8 bl = *(const short8*)(Blo + rowB * 128 + swB);
        acc[n] = __builtin_amdgcn_mfma_f32_16x16x32_bf16(ah, bh, acc[n], 0, 0, 0);
        acc[n] = __builtin_amdgcn_mfma_f32_16x16x32_bf16(ah, bl, acc[n], 0, 0, 0);
        acc[n] = __builtin_amdgcn_mfma_f32_16x16x32_bf16(al, bh, acc[n], 0, 0, 0);
      }
    }
    __syncthreads();
  }
  #pragma unroll
  for (int rr = 0; rr < 4; ++rr){
    int row = i0 + wr * 16 + lhi * 4 + rr;
    #pragma unroll
    for (int n = 0; n < 2; ++n){
      int col = n0 + wc * 32 + n * 16 + l15;
      Cf[(size_t)row * GH + col] = acc[n][rr];
    }
  }
}

// ---------- per-row s_src, s_dst (pre-scaled by log2e) from f32 Wh --------
__global__ __launch_bounds__(256) void skernel(const float* __restrict__ Whf,
                                               const float* __restrict__ asrc,
                                               const float* __restrict__ adst,
                                               float* __restrict__ ss,
                                               float* __restrict__ sd){
  const int lane = threadIdx.x & 63;
  const int i = blockIdx.x * 4 + (threadIdx.x >> 6);
  floatx4 w = *(const floatx4*)(Whf + (size_t)i * GH + lane * 4);
  floatx4 s4 = *(const floatx4*)(asrc + lane * 4);
  floatx4 d4 = *(const floatx4*)(adst + lane * 4);
  float s = 0.f, d = 0.f;
  #pragma unroll
  for (int e = 0; e < 4; ++e){
    s += w[e] * s4[e]; d += w[e] * d4[e];
  }
  #pragma unroll
  for (int off = 32; off; off >>= 1){
    s += __shfl_xor(s, off);
    d += __shfl_xor(d, off);
  }
  if (lane == 0){ ss[i] = s * LOG2E; sd[i] = d * LOG2E; }
}

// --------- per-row masked max (m) and inv exp-sum (1/l); sd cached in LDS --
__global__ __launch_bounds__(256) void rowstats(const u64* __restrict__ mask,
                                                const float* __restrict__ ss,
                                                const float* __restrict__ sd,
                                                float* __restrict__ mm,
                                                float* __restrict__ linv){
  __shared__ float sdl[GN];
  const int tid = threadIdx.x;
  #pragma unroll
  for (int q = 0; q < 4; ++q){
    int idx = (q * 256 + tid) * 4;
    *(floatx4*)(sdl + idx) = *(const floatx4*)(sd + idx);
  }
  __syncthreads();
  const int lane = tid & 63;
  const int i = blockIdx.x * 4 + (tid >> 6);
  const u64* mrow = mask + (size_t)i * 64;
  float mx = -3.0e38f;
  for (int it = 0; it < 64; ++it){
    u64 word = mrow[it];
    float v = sdl[it * 64 + lane];
    uint bit = (uint)(word >> lane) & 1u;
    mx = fmaxf(mx, bit ? v : -3.0e38f);
  }
  #pragma unroll
  for (int off = 32; off; off >>= 1) mx = fmaxf(mx, __shfl_xor(mx, off));
  const float ssi = ss[i];
  float targ = ssi + mx;
  float mmv = fmaxf(targ, 0.2f * targ);
  float sum = 0.f;
  for (int it = 0; it < 64; ++it){
    u64 word = mrow[it];
    float v = sdl[it * 64 + lane];
    uint bit = (uint)(word >> lane) & 1u;
    float a = ssi + v;
    float lr = fmaxf(a, 0.2f * a);
    float p = exp2_(lr - mmv);
    sum += bit ? p : 0.f;
  }
  #pragma unroll
  for (int off = 32; off; off >>= 1) sum += __shfl_xor(sum, off);
  if (lane == 0){ mm[i] = mmv; linv[i] = sum > 0.f ? 1.0f / sum : 0.f; }
}

// ----- fused PV: in-register P (MFMA A-layout), B-only LDS, split-K -------
// block = 128 thr (2 waves), each wave owns 16 rows; tile 32 rows x 256 cols.
// grid (128, KZ) = 1024 blocks -> 4 blocks/CU (LDS 40KB), 2 waves/SIMD.
__global__ __launch_bounds__(128, 2) void gat_pv(const u64* __restrict__ mask,
                                                 const float* __restrict__ ss,
                                                 const float* __restrict__ sd,
                                                 const float* __restrict__ mm,
                                                 const ushort_t* __restrict__ VTh,
                                                 float* __restrict__ partial){
  __shared__ char Blds[2][20480];
  const int tid = threadIdx.x;
  const int lane = tid & 63, w = tid >> 6;
  const int l15 = lane & 15, lhi = lane >> 4;
  const int i0 = blockIdx.x * 32;
  const int kz = blockIdx.y;
  const int ch = tid & 3, c0 = tid >> 2;   // staging: 16B chunk, col base

  const int row = i0 + w * 16 + l15;
  const float ssr = ss[row], mmr = mm[row];
  const u64* mr = mask + (size_t)row * 64;

  floatx4 acc[16] = {};
  short8 g[8];

  auto GLOAD = [&](int kb){
    const int kbase = (kz * KSTEPS + kb) * 32;
    #pragma unroll
    for (int i = 0; i < 8; ++i){
      int c = c0 + 32 * i;
      g[i] = *(const short8*)(VTh + (size_t)c * GN + kbase + ch * 8);
    }
  };
  auto SWRITE = [&](int buf){
    #pragma unroll
    for (int i = 0; i < 8; ++i){
      int c = c0 + 32 * i;
      *(short8*)(Blds[buf] + c * 80 + ch * 16) = g[i];
    }
  };

  GLOAD(0); SWRITE(0); __syncthreads();

  for (int kb = 0; kb < KSTEPS; ++kb){
    if (kb + 1 < KSTEPS) GLOAD(kb + 1);

    const int kstep = kz * KSTEPS + kb;
    const int kbase = kstep * 32;
    floatx4 s0 = *(const floatx4*)(sd + kbase + lhi * 8);
    floatx4 s1 = *(const floatx4*)(sd + kbase + lhi * 8 + 4);
    const int sh = ((kstep & 1) << 5) + lhi * 8;
    uint bits = (uint)(mr[kstep >> 1] >> sh) & 0xffu;
    short8 a;
    #pragma unroll
    for (int e = 0; e < 8; ++e){
      float sv = (e < 4) ? s0[e] : s1[e - 4];
      float t = ssr + sv;
      float lr = fmaxf(t, 0.2f * t);
      float p = exp2_(lr - mmr);
      p = ((bits >> e) & 1u) ? p : 0.0f;
      a[e] = (short)f2bf(p);
    }

    const char* B = Blds[kb & 1];
    #pragma unroll
    for (int n = 0; n < 16; ++n){
      short8 b = *(const short8*)(B + (n * 16 + l15) * 80 + lhi * 16);
      acc[n] = __builtin_amdgcn_mfma_f32_16x16x32_bf16(a, b, acc[n], 0, 0, 0);
    }

    if (kb + 1 < KSTEPS){
      SWRITE((kb + 1) & 1);
      __syncthreads();
    }
  }

  float* pout = partial + (size_t)kz * GN * GH;
  const int rbase = i0 + w * 16 + lhi * 4;
  #pragma unroll
  for (int n = 0; n < 16; ++n){
    int col = n * 16 + l15;
    #pragma unroll
    for (int rr = 0; rr < 4; ++rr)
      pout[(size_t)(rbase + rr) * GH + col] = acc[n][rr];
  }
}

// -- combine split-K partials: scale by 1/l, ReLU, write outb, BN stats ----
__global__ __launch_bounds__(256) void combine_colpart(const float* __restrict__ partial,
                                                       const float* __restrict__ linv,
                                                       float* __restrict__ outb,
                                                       float* __restrict__ part,
                                                       float* __restrict__ partm2){
  const int c = threadIdx.x;
  const int b = blockIdx.x;
  float v[32];
  float s = 0.f;
  #pragma unroll
  for (int r = 0; r < 32; ++r){
    int row = b * 32 + r;
    size_t idx = (size_t)row * GH + c;
    float x = partial[idx];
    #pragma unroll
    for (int z = 1; z < KZ; ++z) x += partial[(size_t)z * GN * GH + idx];
    x = fmaxf(x * linv[row], 0.0f);
    outb[idx] = x;
    v[r] = x; s += x;
  }
  const float mu = s * (1.0f / 32.0f);
  float m2 = 0.f;
  #pragma unroll
  for (int r = 0; r < 32; ++r){ float d = v[r] - mu; m2 += d * d; }
  part[b * GH + c] = s;
  partm2[b * GH + c] = m2;
}

// ---- combine block stats (Chan) in f64 -> per-column scale/bias ----------
__global__ __launch_bounds__(256) void colfin(const float* __restrict__ part,
                                              const float* __restrict__ partm2,
                                              const float* __restrict__ gamma,
                                              const float* __restrict__ beta,
                                              float* __restrict__ scale,
                                              float* __restrict__ bias){
  const int c = threadIdx.x;
  double S = 0.0;
  for (int b = 0; b < 128; ++b) S += (double)part[b * GH + c];
  const double mean = S * (1.0 / 4096.0);
  double M2 = 0.0;
  for (int b = 0; b < 128; ++b){
    double mb = (double)part[b * GH + c] * (1.0 / 32.0);
    double d = mb - mean;
    M2 += (double)partm2[b * GH + c] + 32.0 * d * d;
  }
  const double var = M2 * (1.0 / 4096.0);
  float sc = gamma[c] * (float)(1.0 / sqrt(var + 1e-5));
  scale[c] = sc;
  bias[c] = beta[c] - (float)mean * sc;
}

// ------------------- apply BN: h*scale + bias -> f32 ----------------------
__global__ __launch_bounds__(256) void bnapply(const float* __restrict__ outb,
                                               const float* __restrict__ scale,
                                               const float* __restrict__ bias,
                                               float* __restrict__ dst){
  const int base = (blockIdx.x * 256 + threadIdx.x) * 4;
  const int c = base & (GH - 1);
  floatx4 v = *(const floatx4*)(outb + base);
  floatx4 s = *(const floatx4*)(scale + c);
  floatx4 b = *(const floatx4*)(bias + c);
  #pragma unroll
  for (int e = 0; e < 4; ++e) v[e] = v[e] * s[e] + b[e];
  *(floatx4*)(dst + base) = v;
}

extern "C" void kernel_launch(void* const* d_in, const int* in_sizes, int n_in,
                              void* d_out, int out_size, void* d_ws, size_t ws_size,
                              hipStream_t stream) {
  const float* x      = (const float*)d_in[0];
  const int*   adj    = (const int*)d_in[1];
  const float* W1     = (const float*)d_in[2];
  const float* a1s    = (const float*)d_in[3];
  const float* a1d    = (const float*)d_in[4];
  const float* g1     = (const float*)d_in[5];
  const float* b1     = (const float*)d_in[6];
  const float* W2     = (const float*)d_in[7];
  const float* a2s    = (const float*)d_in[8];
  const float* a2d    = (const float*)d_in[9];
  const float* g2     = (const float*)d_in[10];
  const float* b2     = (const float*)d_in[11];

  char* w = (char*)d_ws;
  auto alloc = [&](size_t bytes){ void* p = (void*)w; w += (bytes + 255) & ~(size_t)255; return p; };
  u64*      mask   = (u64*)alloc((size_t)GN * 64 * 8);          // 2 MB
  ushort_t* W1Th   = (ushort_t*)alloc((size_t)GH * 512 * 2);
  ushort_t* W1Tl   = (ushort_t*)alloc((size_t)GH * 512 * 2);
  ushort_t* W2Th   = (ushort_t*)alloc((size_t)GH * GH * 2);
  ushort_t* W2Tl   = (ushort_t*)alloc((size_t)GH * GH * 2);
  float*    Whf    = (float*)alloc((size_t)GN * GH * 4);        // 4 MB
  ushort_t* VThb   = (ushort_t*)alloc((size_t)GH * GN * 2);     // 2 MB
  float*    hf     = (float*)alloc((size_t)GN * GH * 4);        // 4 MB
  float*    outb   = (float*)alloc((size_t)GN * GH * 4);        // 4 MB
  float*    partial= (float*)alloc((size_t)KZ * GN * GH * 4);   // 32 MB
  float*    ssb    = (float*)alloc(GN * 4);
  float*    sdb    = (float*)alloc(GN * 4);
  float*    mmb    = (float*)alloc(GN * 4);
  float*    linvb  = (float*)alloc(GN * 4);
  float*    part   = (float*)alloc(128 * GH * 4);
  float*    partm2 = (float*)alloc(128 * GH * 4);
  float*    scale  = (float*)alloc(GH * 4);
  float*    bias   = (float*)alloc(GH * 4);

  pack_mask<<<2048, 256, 0, stream>>>(adj, mask);
  transpose_split<<<(512/32)*(GH/32), 256, 0, stream>>>(W1, W1Th, W1Tl, 512, GH);
  transpose_split<<<(GH/32)*(GH/32), 256, 0, stream>>>(W2, W2Th, W2Tl, GH, GH);

  // ---- layer 1 ----
  gemm_split<<<dim3(4, 128), 256, 0, stream>>>(x, W1Th, W1Tl, Whf, 512);
  skernel<<<1024, 256, 0, stream>>>(Whf, a1s, a1d, ssb, sdb);
  transpose_hi<<<(GN/32)*(GH/32), 256, 0, stream>>>(Whf, VThb, GN, GH);
  rowstats<<<1024, 256, 0, stream>>>(mask, ssb, sdb, mmb, linvb);
  gat_pv<<<dim3(GN/32, KZ), 128, 0, stream>>>(mask, ssb, sdb, mmb, VThb, partial);
  combine_colpart<<<128, 256, 0, stream>>>(partial, linvb, outb, part, partm2);
  colfin<<<1, 256, 0, stream>>>(part, partm2, g1, b1, scale, bias);
  bnapply<<<1024, 256, 0, stream>>>(outb, scale, bias, hf);

  // ---- layer 2 ----
  gemm_split<<<dim3(4, 128), 256, 0, stream>>>(hf, W2Th, W2Tl, Whf, 256);
  skernel<<<1024, 256, 0, stream>>>(Whf, a2s, a2d, ssb, sdb);
  transpose_hi<<<(GN/32)*(GH/32), 256, 0, stream>>>(Whf, VThb, GN, GH);
  rowstats<<<1024, 256, 0, stream>>>(mask, ssb, sdb, mmb, linvb);
  gat_pv<<<dim3(GN/32, KZ), 128, 0, stream>>>(mask, ssb, sdb, mmb, VThb, partial);
  combine_colpart<<<128, 256, 0, stream>>>(partial, linvb, outb, part, partm2);
  colfin<<<1, 256, 0, stream>>>(part, partm2, g2, b2, scale, bias);
  bnapply<<<1024, 256, 0, stream>>>(outb, scale, bias, (float*)d_out);
}